// Round 8
// baseline (135.735 us; speedup 1.0000x reference)
//
#include <hip/hip_runtime.h>
#include <stdint.h>

// Problem constants: n_class=32, n_support=16, n_query=16, D=1024;
// query rows Q = 512. Output (512, 32, 1024) fp32.
constexpr int NC = 32, NS = 16, NQ = 512, D = 1024;
constexpr int QPB = 8;     // queries per block = 4 waves x 2 queries/wave

// clang ext-vectors -> VOP3P packed fp32 (v_pk_fma_f32 etc., full-rate 2xf32)
typedef float v2f __attribute__((ext_vector_type(2)));
typedef float v4f __attribute__((ext_vector_type(4)));

// Packed quad term (round-7 proven): {f(t0)+f(t2), f(t1)+f(t3)},
// f(t)=1/(exp2(t)+1), 2 rcp per 4 elements, packed full-rate ops.
// No clamp (validated rounds 3/5/6/7): exp2 can't overflow individually;
// if A*B -> inf, rcp -> 0, contribution 0 (truth ~2^-100); A+B finite.
__device__ __forceinline__ v2f quad_term(v2f t01, v2f t23) {
    v2f A, B;
    A.x = __builtin_amdgcn_exp2f(t01.x);
    A.y = __builtin_amdgcn_exp2f(t01.y);
    B.x = __builtin_amdgcn_exp2f(t23.x);
    B.y = __builtin_amdgcn_exp2f(t23.y);
    A += 1.f;                  // v_pk_add
    B += 1.f;
    v2f prod = A * B;          // v_pk_mul
    v2f sum  = A + B;          // v_pk_add
    v2f r;
    r.x = __builtin_amdgcn_rcpf(prod.x);
    r.y = __builtin_amdgcn_rcpf(prod.y);
    return sum * r;            // fuses into v_pk_fma on accumulate
}

// Direct global->LDS DMA, 16B/lane, zero VGPR round-trip. LDS dest is
// wave-uniform base + lane*16 (linear) — our row-major [16][256] layout
// matches exactly (one call = one support row-quarter of 256 floats).
__device__ __forceinline__ void gload_lds16(const float* g, float* l) {
    __builtin_amdgcn_global_load_lds(
        (const __attribute__((address_space(1))) void*)g,
        (__attribute__((address_space(3))) void*)l,
        16, 0, 0);
}

// launch_bounds(256,2): VGPR cap 128. Caps below the live set (rounds 1/5)
// or live sets above the cap (round 6) spill catastrophically — tripwire:
// WRITE_SIZE must stay exactly 65536 KB. Staging now costs ZERO VGPRs.
__global__ __launch_bounds__(256, 2)
void proto_attn_kernel(const float* __restrict__ data, float* __restrict__ out) {
    const int c    = blockIdx.x;   // class
    const int qt   = blockIdx.y;   // query tile
    const int tid  = threadIdx.x;
    const int wave = tid >> 6;
    const int lane = tid & 63;

    // Double-buffered d-quarter of support[c]: 2 x (16 rows x 256 floats) = 32 KB.
    __shared__ __align__(16) float buf[2][NS * 256];

    const float* sup = data + (size_t)c * NS * D;

    // async-stage quarter p into buf[b]: per wave 4 rows, 1 DMA each.
    auto stage = [&](int p, int b) {
        #pragma unroll
        for (int r = 0; r < 4; ++r) {
            int row = 4 * wave + r;
            gload_lds16(sup + row * D + p * 256 + lane * 4,
                        &buf[b][row * 256]);
        }
    };

    const float K = 2.88539008177792681472f;   // 2*log2(e); tanh(x)=1-2/(exp2(Kx)+1)
    const int q0 = qt * QPB + wave * 2;
    const v4f* qg0 = reinterpret_cast<const v4f*>(data + (size_t)(NC * NS + q0) * D);
    const v4f* qg1 = qg0 + 256;   // next query row

    stage(0, 0);   // prologue DMA; latency hidden under the query loads below

    // queries, all 4 d-quarters, pre-scaled by K (32 VGPR, held)
    v4f qa[4], qb[4];
    #pragma unroll
    for (int j = 0; j < 4; ++j) {
        qa[j] = qg0[64 * j + lane] * K;
        qb[j] = qg1[64 * j + lane] * K;
    }
    __syncthreads();   // implicit vmcnt(0) drain -> quarter 0 staged

    float sc0[NS], sc1[NS];
    #pragma unroll
    for (int s = 0; s < NS; ++s) { sc0[s] = 0.f; sc1[s] = 0.f; }

    // ---- score phases p=0..3: DMA next quarter into other buffer, compute
    //      current; one barrier per phase (DMA retires under ~1500cy compute)
    #pragma unroll
    for (int p = 0; p < 4; ++p) {
        stage((p + 1) & 3, (p + 1) & 1);   // p=3 wraps: quarter 0 -> buf0 (for proto)
        const v4f* B = reinterpret_cast<const v4f*>(buf[p & 1]);
        const v4f qA = qa[p], qB = qb[p];
        #pragma unroll
        for (int s = 0; s < NS; ++s) {
            v4f sv = B[(s << 6) + lane];
            v2f t0 = quad_term(sv.xy * qA.xy, sv.zw * qA.zw);
            v2f t1 = quad_term(sv.xy * qB.xy, sv.zw * qB.zw);
            sc0[s] += t0.x + t0.y;   // collapse keeps reg footprint low
            sc1[s] += t1.x + t1.y;
        }
        __syncthreads();
    }
    // buf0 holds quarter 0 again.

    stage(1, 1);   // prefetch quarter 1 under the reduction + softmax

    // ---- wave64 butterfly reduction: sc[q][s] = D - 2*sum_d f ----
    #pragma unroll
    for (int s = 0; s < NS; ++s) {
        float r0 = sc0[s], r1 = sc1[s];
        #pragma unroll
        for (int m = 32; m >= 1; m >>= 1) {
            r0 += __shfl_xor(r0, m, 64);
            r1 += __shfl_xor(r1, m, 64);
        }
        sc0[s] = (float)D - 2.f * r0;
        sc1[s] = (float)D - 2.f * r1;
    }

    // ---- softmax over s (16 values, replicated per lane) ----
    const float L2E = 1.44269504088896340736f;
    float m0 = sc0[0], m1 = sc1[0];
    #pragma unroll
    for (int s = 1; s < NS; ++s) { m0 = fmaxf(m0, sc0[s]); m1 = fmaxf(m1, sc1[s]); }
    float sum0 = 0.f, sum1 = 0.f;
    #pragma unroll
    for (int s = 0; s < NS; ++s) {
        sc0[s] = __builtin_amdgcn_exp2f((sc0[s] - m0) * L2E);
        sc1[s] = __builtin_amdgcn_exp2f((sc1[s] - m1) * L2E);
        sum0 += sc0[s];
        sum1 += sc1[s];
    }
    const float inv0 = __builtin_amdgcn_rcpf(sum0);
    const float inv1 = __builtin_amdgcn_rcpf(sum1);
    #pragma unroll
    for (int s = 0; s < NS; ++s) { sc0[s] *= inv0; sc1[s] *= inv1; }

    v4f* og0 = reinterpret_cast<v4f*>(out + ((size_t)q0 * NC + c) * D);
    v4f* og1 = reinterpret_cast<v4f*>(out + ((size_t)(q0 + 1) * NC + c) * D);

    // ---- proto phases p=0..3 (packed FMAs), double-buffered like score ----
    // p=0 reads buf0 (q0, staged at score p=3); q1 prefetched pre-softmax;
    // p=1 stages q2->buf0, p=2 stages q3->buf1.
    #pragma unroll
    for (int p = 0; p < 4; ++p) {
        if (p == 1 || p == 2) stage(p + 1, (p + 1) & 1);
        const v4f* B = reinterpret_cast<const v4f*>(buf[p & 1]);
        v2f oxy0 = 0.f, ozw0 = 0.f, oxy1 = 0.f, ozw1 = 0.f;
        #pragma unroll
        for (int s = 0; s < NS; ++s) {
            v4f sv = B[(s << 6) + lane];
            oxy0 += sv.xy * sc0[s];   // v_pk_fma_f32
            ozw0 += sv.zw * sc0[s];
            oxy1 += sv.xy * sc1[s];
            ozw1 += sv.zw * sc1[s];
        }
        v4f r0, r1;
        r0.xy = oxy0; r0.zw = ozw0;
        r1.xy = oxy1; r1.zw = ozw1;
        og0[(p << 6) + lane] = r0;
        og1[(p << 6) + lane] = r1;
        if (p < 3) __syncthreads();
    }
}

extern "C" void kernel_launch(void* const* d_in, const int* in_sizes, int n_in,
                              void* d_out, int out_size, void* d_ws, size_t ws_size,
                              hipStream_t stream) {
    (void)in_sizes; (void)n_in; (void)out_size; (void)d_ws; (void)ws_size;
    const float* data = (const float*)d_in[0];
    float* out = (float*)d_out;
    dim3 grid(NC, NQ / QPB);   // 32 classes x 64 query tiles = 2048 blocks
    proto_attn_kernel<<<grid, dim3(256), 0, stream>>>(data, out);
}

// Round 9
// 134.895 us; speedup vs baseline: 1.0062x; 1.0062x over previous
//
#include <hip/hip_runtime.h>
#include <stdint.h>

// Problem constants: n_class=32, n_support=16, n_query=16, D=1024;
// query rows Q = 512. Output (512, 32, 1024) fp32.
constexpr int NC = 32, NS = 16, NQ = 512, D = 1024;
constexpr int QPB = 8;     // queries per block = 4 waves x 2 queries/wave

// clang ext-vectors -> VOP3P packed fp32 (v_pk_fma_f32 etc., full-rate 2xf32)
typedef float v2f __attribute__((ext_vector_type(2)));
typedef float v4f __attribute__((ext_vector_type(4)));

// Packed quad term (round-7 proven): {f(t0)+f(t2), f(t1)+f(t3)},
// f(t)=1/(exp2(t)+1), 2 rcp per 4 elements, packed full-rate ops.
// No clamp (validated rounds 3..8): exp2 can't overflow individually for
// this data; if A*B -> inf, rcp -> 0, contribution 0 (truth ~2^-100);
// A+B stays finite so no NaN.
__device__ __forceinline__ v2f quad_term(v2f t01, v2f t23) {
    v2f A, B;
    A.x = __builtin_amdgcn_exp2f(t01.x);
    A.y = __builtin_amdgcn_exp2f(t01.y);
    B.x = __builtin_amdgcn_exp2f(t23.x);
    B.y = __builtin_amdgcn_exp2f(t23.y);
    A += 1.f;                  // v_pk_add
    B += 1.f;
    v2f prod = A * B;          // v_pk_mul
    v2f sum  = A + B;          // v_pk_add
    v2f r;
    r.x = __builtin_amdgcn_rcpf(prod.x);
    r.y = __builtin_amdgcn_rcpf(prod.y);
    return sum * r;            // fuses into v_pk_fma on accumulate
}

// Direct global->LDS DMA, 16B/lane, zero VGPR round-trip. LDS dest is
// wave-uniform base + lane*16 (linear); one call = one support row-quarter.
__device__ __forceinline__ void gload_lds16(const float* g, float* l) {
    __builtin_amdgcn_global_load_lds(
        (const __attribute__((address_space(1))) void*)g,
        (__attribute__((address_space(3))) void*)l,
        16, 0, 0);
}

// launch_bounds(256,2): VGPR cap 128 (caps below the live set spill — rounds
// 1/5/6; tripwire: WRITE_SIZE must stay exactly 65536 KB).
// Schedule (round-9): 4 barriers total. Score = 4 DMA-double-buffered
// quarter phases (round-8's good half, ~700cy compute covers each DMA).
// Everything after the last score phase is BARRIER-FREE: reduction, softmax,
// and proto (which re-reads the L2-hot support directly from global —
// independent loads + 16-deep FMA chains tolerate L2 latency via TLP,
// unlike score). Round 8 showed proto phases (~260cy) are too thin to host
// pipelined DMA stages: 8 barriers x full vmcnt drain cost ~7.4us.
__global__ __launch_bounds__(256, 2)
void proto_attn_kernel(const float* __restrict__ data, float* __restrict__ out) {
    const int c    = blockIdx.x;   // class
    const int qt   = blockIdx.y;   // query tile
    const int tid  = threadIdx.x;
    const int wave = tid >> 6;
    const int lane = tid & 63;

    // Double-buffered d-quarter of support[c]: 2 x (16 rows x 256 floats) = 32 KB.
    __shared__ __align__(16) float buf[2][NS * 256];

    const float* sup = data + (size_t)c * NS * D;
    const v4f*   sg4 = reinterpret_cast<const v4f*>(sup);

    // async-stage quarter p into buf[b]: per wave 4 rows, 1 DMA each.
    auto stage = [&](int p, int b) {
        #pragma unroll
        for (int r = 0; r < 4; ++r) {
            int row = 4 * wave + r;
            gload_lds16(sup + row * D + p * 256 + lane * 4,
                        &buf[b][row * 256]);
        }
    };

    const float K = 2.88539008177792681472f;   // 2*log2(e); tanh(x)=1-2/(exp2(Kx)+1)
    const int q0 = qt * QPB + wave * 2;
    const v4f* qg0 = reinterpret_cast<const v4f*>(data + (size_t)(NC * NS + q0) * D);
    const v4f* qg1 = qg0 + 256;   // next query row

    stage(0, 0);       // prologue DMA
    __syncthreads();   // implicit vmcnt(0) drain -> quarter 0 staged

    float sc0[NS], sc1[NS];
    #pragma unroll
    for (int s = 0; s < NS; ++s) { sc0[s] = 0.f; sc1[s] = 0.f; }

    // ---- score phases p=0..3: DMA next quarter into other buffer, compute
    //      current (~700cy covers the DMA); barrier after p=0,1,2 only.
    //      Queries loaded per-phase (8 regs live, L1/L2-hot) instead of
    //      holding all 32 — aims for the <=64-VGPR occupancy bucket.
    #pragma unroll
    for (int p = 0; p < 4; ++p) {
        if (p < 3) stage(p + 1, (p + 1) & 1);
        v4f qA = qg0[(p << 6) + lane] * K;
        v4f qB = qg1[(p << 6) + lane] * K;
        const v4f* B = reinterpret_cast<const v4f*>(buf[p & 1]);
        #pragma unroll
        for (int s = 0; s < NS; ++s) {
            v4f sv = B[(s << 6) + lane];
            v2f t0 = quad_term(sv.xy * qA.xy, sv.zw * qA.zw);
            v2f t1 = quad_term(sv.xy * qB.xy, sv.zw * qB.zw);
            sc0[s] += t0.x + t0.y;   // collapse keeps reg footprint low
            sc1[s] += t1.x + t1.y;
        }
        if (p < 3) __syncthreads();
    }
    // No barriers from here to kernel exit: waves decouple and drain freely.

    // ---- wave64 butterfly reduction: sc[q][s] = D - 2*sum_d f ----
    #pragma unroll
    for (int s = 0; s < NS; ++s) {
        float r0 = sc0[s], r1 = sc1[s];
        #pragma unroll
        for (int m = 32; m >= 1; m >>= 1) {
            r0 += __shfl_xor(r0, m, 64);
            r1 += __shfl_xor(r1, m, 64);
        }
        sc0[s] = (float)D - 2.f * r0;
        sc1[s] = (float)D - 2.f * r1;
    }

    // ---- softmax over s (16 values, replicated per lane) ----
    const float L2E = 1.44269504088896340736f;
    float m0 = sc0[0], m1 = sc1[0];
    #pragma unroll
    for (int s = 1; s < NS; ++s) { m0 = fmaxf(m0, sc0[s]); m1 = fmaxf(m1, sc1[s]); }
    float sum0 = 0.f, sum1 = 0.f;
    #pragma unroll
    for (int s = 0; s < NS; ++s) {
        sc0[s] = __builtin_amdgcn_exp2f((sc0[s] - m0) * L2E);
        sc1[s] = __builtin_amdgcn_exp2f((sc1[s] - m1) * L2E);
        sum0 += sc0[s];
        sum1 += sc1[s];
    }
    const float inv0 = __builtin_amdgcn_rcpf(sum0);
    const float inv1 = __builtin_amdgcn_rcpf(sum1);
    #pragma unroll
    for (int s = 0; s < NS; ++s) { sc0[s] *= inv0; sc1[s] *= inv1; }

    v4f* og0 = reinterpret_cast<v4f*>(out + ((size_t)q0 * NC + c) * D);
    v4f* og1 = reinterpret_cast<v4f*>(out + ((size_t)(q0 + 1) * NC + c) * D);

    // ---- proto straight from global (L2-hot: score just streamed it).
    //      16 independent loads + 16-deep independent FMA chains per quarter;
    //      no LDS, no restage, no barriers.
    #pragma unroll
    for (int p = 0; p < 4; ++p) {
        v2f oxy0 = 0.f, ozw0 = 0.f, oxy1 = 0.f, ozw1 = 0.f;
        #pragma unroll
        for (int s = 0; s < NS; ++s) {
            v4f sv = sg4[(s << 8) + (p << 6) + lane];
            oxy0 += sv.xy * sc0[s];   // v_pk_fma_f32
            ozw0 += sv.zw * sc0[s];
            oxy1 += sv.xy * sc1[s];
            ozw1 += sv.zw * sc1[s];
        }
        v4f r0, r1;
        r0.xy = oxy0; r0.zw = ozw0;
        r1.xy = oxy1; r1.zw = ozw1;
        og0[(p << 6) + lane] = r0;
        og1[(p << 6) + lane] = r1;
    }
}

extern "C" void kernel_launch(void* const* d_in, const int* in_sizes, int n_in,
                              void* d_out, int out_size, void* d_ws, size_t ws_size,
                              hipStream_t stream) {
    (void)in_sizes; (void)n_in; (void)out_size; (void)d_ws; (void)ws_size;
    const float* data = (const float*)d_in[0];
    float* out = (float*)d_out;
    dim3 grid(NC, NQ / QPB);   // 32 classes x 64 query tiles = 2048 blocks
    proto_attn_kernel<<<grid, dim3(256), 0, stream>>>(data, out);
}

// Round 10
// 133.686 us; speedup vs baseline: 1.0153x; 1.0090x over previous
//
#include <hip/hip_runtime.h>
#include <stdint.h>

// Problem constants: n_class=32, n_support=16, n_query=16, D=1024;
// query rows Q = 512. Output (512, 32, 1024) fp32.
constexpr int NC = 32, NS = 16, NQ = 512, D = 1024;
constexpr int QPB = 8;     // queries per block = 4 waves x 2 queries/wave

// clang ext-vectors -> VOP3P packed fp32 (v_pk_fma_f32 etc., full-rate 2xf32)
typedef float v2f __attribute__((ext_vector_type(2)));
typedef float v4f __attribute__((ext_vector_type(4)));

// Packed quad accumulate (round-7 proven math, collapse folded into 2 fma):
// acc += f(t0)+f(t1)+f(t2)+f(t3), f(t)=1/(exp2(t)+1), 2 rcp per 4 elements.
// No clamp (validated rounds 3..9): exp2 can't overflow individually for
// this data; if A*B -> inf, rcp -> 0, contribution 0 (truth ~2^-100);
// A+B stays finite so no NaN.
__device__ __forceinline__ void quad_acc(v2f t01, v2f t23, float& acc) {
    v2f A, B;
    A.x = __builtin_amdgcn_exp2f(t01.x);
    A.y = __builtin_amdgcn_exp2f(t01.y);
    B.x = __builtin_amdgcn_exp2f(t23.x);
    B.y = __builtin_amdgcn_exp2f(t23.y);
    A += 1.f;                  // v_pk_add
    B += 1.f;
    v2f prod = A * B;          // v_pk_mul
    v2f sum  = A + B;          // v_pk_add
    acc = fmaf(sum.x, __builtin_amdgcn_rcpf(prod.x), acc);
    acc = fmaf(sum.y, __builtin_amdgcn_rcpf(prod.y), acc);
}

// Direct global->LDS DMA, 16B/lane, zero VGPR round-trip (round-8 proven).
// LDS dest = wave-uniform base + lane*16 (linear); one call = 256 floats.
__device__ __forceinline__ void gload_lds16(const float* g, float* l) {
    __builtin_amdgcn_global_load_lds(
        (const __attribute__((address_space(1))) void*)g,
        (__attribute__((address_space(3))) void*)l,
        16, 0, 0);
}

// Round-10 schedule: TWO barriers total.
//   stage h0 (DMA) ; bar0 ; { stage h1 under score-h0 (~1400cy >> DMA) } ;
//   bar1 ; score-h1 ; then BARRIER-FREE to exit: reduction, softmax, proto
//   reading both halves still resident in LDS (64 KB), stores.
// Lessons encoded: staging must cost 0 VGPR (rounds 1/5/6/9: any big load
// batch held in VGPRs spills or kills occupancy); back half must read LDS
// not global (round 9); barrier drains are the idle term (round 8: 8 thin
// barriers cost ~7us vs round 7).
// launch_bounds(256,2): VGPR cap 128 — LDS caps residency at 2 blocks/CU,
// so VGPR up to 128 is free. Tripwire: WRITE_SIZE == 65536 KB exactly.
__global__ __launch_bounds__(256, 2)
void proto_attn_kernel(const float* __restrict__ data, float* __restrict__ out) {
    const int c    = blockIdx.x;   // class
    const int qt   = blockIdx.y;   // query tile
    const int tid  = threadIdx.x;
    const int wave = tid >> 6;
    const int lane = tid & 63;

    // Both d-halves of support[c] resident: 2 x (16 rows x 512 floats) = 64 KB.
    __shared__ __align__(16) float buf[2][NS * 512];

    const float* sup = data + (size_t)c * NS * D;

    // async-stage half h: per wave 4 rows x 2 DMAs (8 instrs, 0 VGPR).
    auto stage = [&](int h) {
        #pragma unroll
        for (int r = 0; r < 4; ++r) {
            int row = 4 * wave + r;
            const float* g = sup + row * D + h * 512 + lane * 4;
            gload_lds16(g,       &buf[h][row * 512]);
            gload_lds16(g + 256, &buf[h][row * 512 + 256]);
        }
    };

    const float K = 2.88539008177792681472f;   // 2*log2(e); tanh(x)=1-2/(exp2(Kx)+1)
    const int q0 = qt * QPB + wave * 2;
    const v4f* qg0 = reinterpret_cast<const v4f*>(data + (size_t)(NC * NS + q0) * D);
    const v4f* qg1 = qg0 + 256;   // next query row

    stage(0);   // prologue DMA; retires under the query loads below

    // queries, all 4 d-quarters, pre-scaled by K (32 VGPR, held — free here)
    v4f qa[4], qb[4];
    #pragma unroll
    for (int j = 0; j < 4; ++j) {
        qa[j] = qg0[64 * j + lane] * K;
        qb[j] = qg1[64 * j + lane] * K;
    }
    __syncthreads();   // bar0: vmcnt drain -> h0 staged & visible

    float sc0[NS], sc1[NS];
    #pragma unroll
    for (int s = 0; s < NS; ++s) { sc0[s] = 0.f; sc1[s] = 0.f; }

    stage(1);   // DMA h1 into the other half; covered by ~1400cy score-h0

    // ---- score over h0 ----
    {
        const v4f* B = reinterpret_cast<const v4f*>(buf[0]);
        #pragma unroll
        for (int s = 0; s < NS; ++s) {
            #pragma unroll
            for (int j = 0; j < 2; ++j) {
                v4f sv = B[(s << 7) + (j << 6) + lane];
                quad_acc(sv.xy * qa[j].xy, sv.zw * qa[j].zw, sc0[s]);
                quad_acc(sv.xy * qb[j].xy, sv.zw * qb[j].zw, sc1[s]);
            }
        }
    }
    __syncthreads();   // bar1: vmcnt drain -> h1 staged & visible

    // ---- score over h1 ----  (LAST barrier was bar1; free-run from here)
    {
        const v4f* B = reinterpret_cast<const v4f*>(buf[1]);
        #pragma unroll
        for (int s = 0; s < NS; ++s) {
            #pragma unroll
            for (int j = 0; j < 2; ++j) {
                v4f sv = B[(s << 7) + (j << 6) + lane];
                quad_acc(sv.xy * qa[2 + j].xy, sv.zw * qa[2 + j].zw, sc0[s]);
                quad_acc(sv.xy * qb[2 + j].xy, sv.zw * qb[2 + j].zw, sc1[s]);
            }
        }
    }

    // ---- wave64 butterfly reduction: sc[q][s] = D - 2*sum_d f ----
    #pragma unroll
    for (int s = 0; s < NS; ++s) {
        float r0 = sc0[s], r1 = sc1[s];
        #pragma unroll
        for (int m = 32; m >= 1; m >>= 1) {
            r0 += __shfl_xor(r0, m, 64);
            r1 += __shfl_xor(r1, m, 64);
        }
        sc0[s] = (float)D - 2.f * r0;
        sc1[s] = (float)D - 2.f * r1;
    }

    // ---- softmax over s (16 values, replicated per lane) ----
    const float L2E = 1.44269504088896340736f;
    float m0 = sc0[0], m1 = sc1[0];
    #pragma unroll
    for (int s = 1; s < NS; ++s) { m0 = fmaxf(m0, sc0[s]); m1 = fmaxf(m1, sc1[s]); }
    float sum0 = 0.f, sum1 = 0.f;
    #pragma unroll
    for (int s = 0; s < NS; ++s) {
        sc0[s] = __builtin_amdgcn_exp2f((sc0[s] - m0) * L2E);
        sc1[s] = __builtin_amdgcn_exp2f((sc1[s] - m1) * L2E);
        sum0 += sc0[s];
        sum1 += sc1[s];
    }
    const float inv0 = __builtin_amdgcn_rcpf(sum0);
    const float inv1 = __builtin_amdgcn_rcpf(sum1);
    #pragma unroll
    for (int s = 0; s < NS; ++s) { sc0[s] *= inv0; sc1[s] *= inv1; }

    v4f* og0 = reinterpret_cast<v4f*>(out + ((size_t)q0 * NC + c) * D);
    v4f* og1 = reinterpret_cast<v4f*>(out + ((size_t)(q0 + 1) * NC + c) * D);

    // ---- proto from resident LDS (both halves), packed FMAs, no barriers ----
    #pragma unroll
    for (int p = 0; p < 4; ++p) {
        const v4f* B = reinterpret_cast<const v4f*>(buf[p >> 1]);
        const int jo = (p & 1) << 6;
        v2f oxy0 = 0.f, ozw0 = 0.f, oxy1 = 0.f, ozw1 = 0.f;
        #pragma unroll
        for (int s = 0; s < NS; ++s) {
            v4f sv = B[(s << 7) + jo + lane];
            oxy0 += sv.xy * sc0[s];   // v_pk_fma_f32
            ozw0 += sv.zw * sc0[s];
            oxy1 += sv.xy * sc1[s];
            ozw1 += sv.zw * sc1[s];
        }
        v4f r0, r1;
        r0.xy = oxy0; r0.zw = ozw0;
        r1.xy = oxy1; r1.zw = ozw1;
        og0[(p << 6) + lane] = r0;
        og1[(p << 6) + lane] = r1;
    }
}

extern "C" void kernel_launch(void* const* d_in, const int* in_sizes, int n_in,
                              void* d_out, int out_size, void* d_ws, size_t ws_size,
                              hipStream_t stream) {
    (void)in_sizes; (void)n_in; (void)out_size; (void)d_ws; (void)ws_size;
    const float* data = (const float*)d_in[0];
    float* out = (float*)d_out;
    dim3 grid(NC, NQ / QPB);   // 32 classes x 64 query tiles = 2048 blocks
    proto_attn_kernel<<<grid, dim3(256), 0, stream>>>(data, out);
}